// Round 12
// baseline (196.025 us; speedup 1.0000x reference)
//
#include <hip/hip_runtime.h>
#include <stdint.h>

#define VOCAB 16384
#define NB 32
#define NTOK 8224      // 32*257
#define MTILES 65      // M tiles of 128 rows
#define MP 8320        // MTILES*128
#define NBY 128        // N tiles of 128 cols
#define TILE_BYTES 65536    // 128 rows x 256 K x 2B f16
#define NLOSS 2056          // loss partial blocks (NTOK/4)
#define MWIN 2.25e-3f       // |sim_f16 - sim_fp32| window (2*margin) + mantissa-embed slack
#define TOKCHUNKS 520       // token pack chunks

typedef _Float16 half8 __attribute__((ext_vector_type(8)));
typedef float f4 __attribute__((ext_vector_type(4)));
typedef float f16v __attribute__((ext_vector_type(16)));
typedef __attribute__((address_space(1))) const uint32_t* gas_t;
typedef __attribute__((address_space(3))) uint32_t* las_t;

__device__ __forceinline__ void async16(const void* g, void* l) {
    __builtin_amdgcn_global_load_lds((gas_t)g, (las_t)l, 16, 0, 0);
}

__device__ __forceinline__ unsigned long long key64(float v, int idx) {
    unsigned u = __float_as_uint(v);
    u = (u & 0x80000000u) ? ~u : (u | 0x80000000u);
    return ((unsigned long long)u << 32) | (unsigned)(~idx);   // order: val desc, idx asc
}

__device__ __forceinline__ float keyval(unsigned long long k) {
    unsigned u = (unsigned)(k >> 32);
    u = (u & 0x80000000u) ? (u & 0x7fffffffu) : ~u;
    return __uint_as_float(u);
}

__device__ __forceinline__ void merge2(unsigned long long& k1, unsigned long long& k2,
                                       unsigned long long p1, unsigned long long p2) {
    unsigned long long lo = k1 < p1 ? k1 : p1;           // top-2 of {k1,k2,p1,p2}, k2<=k1, p2<=p1
    k1 = k1 > p1 ? k1 : p1;
    unsigned long long m2 = k2 > p2 ? k2 : p2;
    k2 = lo > m2 ? lo : m2;
}

// Packed fragment layout for mfma_f32_32x32x16_f16 (both operands — layouts are symmetric):
// tile 128 rows x 256 k, unit = [ks(16)][rb(4)][lane(64) x 16B];
// lane = (r&31) + 32*(oct&1), oct = k>>3, ks = oct>>1, rb = (r>>5)&3.

// ---------- prep: patch transpose (blocks 0..511, id 0 zeroes used) || W pack (blocks 512..1535) ----------
__global__ __launch_bounds__(256) void k_prep(const float* __restrict__ patch, const float* __restrict__ W,
                                              float* __restrict__ tok, char* __restrict__ bpk,
                                              float* __restrict__ nwv, unsigned int* __restrict__ used) {
    __shared__ float buf[4290];          // union: patch half uses [64][65]; W half uses [16][264]
    __shared__ float pr[16][16];
    __shared__ float sn[16];
    int id = blockIdx.x;
    int tid = threadIdx.x;
    if (id < 512) {
        if (id == 0) {
            for (int i = tid; i < VOCAB / 32; i += 256) used[i] = 0u;
        }
        int c0 = (id & 3) * 64, p0 = ((id >> 2) & 3) * 64, b = id >> 4;
        int l = tid & 63, w = tid >> 6;
        const float* src = patch + b * 65536;
#pragma unroll
        for (int i = 0; i < 16; ++i) {
            int row = i * 4 + w;
            buf[row * 65 + l] = src[(c0 + row) * 256 + p0 + l];
        }
        __syncthreads();
#pragma unroll
        for (int i = 0; i < 16; ++i) {
            int prow = i * 4 + w;
            tok[(b * 257 + 1 + p0 + prow) * 256 + c0 + l] = buf[l * 65 + prow];
        }
    } else {
        // W pack: g = id-512 in 0..1023, rows g*16 .. g*16+15
        int g = id - 512;
        int row0 = g * 16;
        int rr = tid >> 4, cb = tid & 15;
        const float* sp = W + (size_t)(row0 + rr) * 256 + cb * 16;
        float psum = 0.0f;
#pragma unroll
        for (int i = 0; i < 4; ++i) {
            float4 v = *(const float4*)(sp + i * 4);
            *(float4*)&buf[rr * 264 + cb * 16 + i * 4] = v;
            psum += v.x * v.x + v.y * v.y + v.z * v.z + v.w * v.w;
        }
        pr[rr][cb] = psum;
        __syncthreads();
        if (tid < 16) {
            float s = 0.0f;
#pragma unroll
            for (int j = 0; j < 16; ++j) s += pr[tid][j];
            float nv = fmaxf(sqrtf(s), 1e-12f);
            sn[tid] = nv;
            nwv[row0 + tid] = nv;
        }
        __syncthreads();
        int c = tid & 63, pair = tid >> 6;
        int m = c & 15, jb = (c >> 4) * 8;
        float inv = 1.0f / sn[m];
        int rlow = (g & 1) * 16 + m;         // r & 31
        int rb = (g >> 1) & 3;
        char* tbase = bpk + (size_t)(g >> 3) * TILE_BYTES + rb * 1024;
#pragma unroll
        for (int it = 0; it < 2; ++it) {
            int k32 = it * 4 + pair;
            int oI = k32 * 4 + (c >> 4);     // k-octet 0..31
            const float* rowp = &buf[m * 264 + k32 * 32 + jb];
            half8 o;
#pragma unroll
            for (int j = 0; j < 8; ++j) o[j] = (_Float16)(rowp[j] * inv);
            *(half8*)(tbase + (size_t)(oI >> 1) * 4096 + (size_t)(rlow + 32 * (oI & 1)) * 16) = o;
        }
    }
}

// ---------- token pack: normalized rows -> f16, 32x32 fragment order; saves norms ----------
__global__ __launch_bounds__(256) void k_packA(const float* __restrict__ tok, const float* __restrict__ cls,
                                               char* __restrict__ apk, float* __restrict__ ntokv) {
    __shared__ float t[16][264];
    __shared__ float pr[16][16];
    __shared__ float sn[16];
    int g = blockIdx.x;              // 16-row chunk id, 0..519
    int row0 = g * 16;
    int tid = threadIdx.x;
    int rr = tid >> 4, cb = tid & 15;
    int grow = row0 + rr;
    int b = grow / 257, s = grow - b * 257;
    const float* sp = (s == 0 && grow < NTOK) ? (cls + (size_t)b * 256 + cb * 16)
                                              : (tok + (size_t)grow * 256 + cb * 16);
    float psum = 0.0f;
#pragma unroll
    for (int i = 0; i < 4; ++i) {
        float4 v = (grow < NTOK) ? *(const float4*)(sp + i * 4) : make_float4(0.f, 0.f, 0.f, 0.f);
        *(float4*)&t[rr][cb * 16 + i * 4] = v;
        psum += v.x * v.x + v.y * v.y + v.z * v.z + v.w * v.w;
    }
    pr[rr][cb] = psum;
    __syncthreads();
    if (tid < 16) {
        float s2 = 0.0f;
#pragma unroll
        for (int j = 0; j < 16; ++j) s2 += pr[tid][j];
        float nv = fmaxf(sqrtf(s2), 1e-12f);
        sn[tid] = nv;
        ntokv[row0 + tid] = nv;
    }
    __syncthreads();
    int c = tid & 63, pair = tid >> 6;
    int m = c & 15, jb = (c >> 4) * 8;
    float inv = 1.0f / sn[m];
    int rlow = (g & 1) * 16 + m;
    int rb = (g >> 1) & 3;
    char* tbase = apk + (size_t)(g >> 3) * TILE_BYTES + rb * 1024;
#pragma unroll
    for (int it = 0; it < 2; ++it) {
        int k32 = it * 4 + pair;
        int oI = k32 * 4 + (c >> 4);
        const float* rowp = &t[m][k32 * 32 + jb];
        half8 o;
#pragma unroll
        for (int j = 0; j < 8; ++j) o[j] = (_Float16)(rowp[j] * inv);
        *(half8*)(tbase + (size_t)(oI >> 1) * 4096 + (size_t)(rlow + 32 * (oI & 1)) * 16) = o;
    }
}

// ---------- sim: 32x32x16 f16 MFMA; A whole-tile in LDS (once), B direct global->reg ----------
// R5/R11 schedule (best measured), MFMA shape upgraded: measured ceiling 2495 vs 2075 TF,
// half the MFMA instructions, cross-lane top-2 merge shrinks 2 steps -> 1.
// OPERAND-SWAPPED mfma(B,A) -> C^T: token = ln&31 (col); n = (reg&3)+8*(reg>>2)+4*(ln>>5) (row).
__global__ __launch_bounds__(256) void k_sim(const char* __restrict__ apk, const char* __restrict__ bpk,
                                             unsigned long long* __restrict__ pb) {
    __shared__ char lds[65536];                        // A: full 128x256 tile, never overwritten
    // XCD-aware supertile swizzle (R4-proven: FETCH 602->90 MB)
    int id = blockIdx.x;             // 0..8319
    int xcd = id & 7, r = id >> 3;
    int st = r / 104, within = r % 104;
    int stid = xcd * 10 + st;        // 0..79
    int sx = stid % 5, sy = stid / 5;
    int bx = sx * 13 + within % 13;  // 0..64
    int by = sy * 8 + within / 13;   // 0..127

    int tid = threadIdx.x;
    int ln = tid & 63, wv = tid >> 6;
    int mh = wv >> 1, nh = wv & 1;   // token-half / n-half (64 wide each)
    const char* abase = apk + (size_t)bx * TILE_BYTES;
    const half8* Bg = (const half8*)(bpk + (size_t)by * TILE_BYTES);   // frag (ks*4+rb)*64+ln

    f16v acc[2][2];
#pragma unroll
    for (int i = 0; i < 2; ++i)
#pragma unroll
        for (int j = 0; j < 2; ++j)
#pragma unroll
            for (int e = 0; e < 16; ++e) acc[i][j][e] = 0.0f;

    half8 b0[4][2], b1[4][2];
#define LOADB(DST, P)                                                                 \
    _Pragma("unroll")                                                                 \
    for (int kk = 0; kk < 4; ++kk)                                                    \
        _Pragma("unroll")                                                             \
        for (int nt = 0; nt < 2; ++nt)                                                \
            DST[kk][nt] = Bg[(((P) * 4 + kk) * 4 + nh * 2 + nt) * 64 + ln];

#define FRAGS(P)                                                                      \
    half8 ah[4][2];                                                                   \
    _Pragma("unroll")                                                                 \
    for (int kk = 0; kk < 4; ++kk)                                                    \
        _Pragma("unroll")                                                             \
        for (int tt = 0; tt < 2; ++tt)                                                \
            ah[kk][tt] = *(const half8*)(lds + (size_t)(((P) * 4 + kk) * 4 + mh * 2 + tt) * 1024 + ln * 16);

#define DOMFMA(BH)                                                                    \
    __builtin_amdgcn_s_setprio(1);                                                    \
    _Pragma("unroll")                                                                 \
    for (int kk = 0; kk < 4; ++kk)                                                    \
        _Pragma("unroll")                                                             \
        for (int tt = 0; tt < 2; ++tt)                                                \
            _Pragma("unroll")                                                         \
            for (int nt = 0; nt < 2; ++nt)                                            \
                acc[tt][nt] = __builtin_amdgcn_mfma_f32_32x32x16_f16(BH[kk][nt], ah[kk][tt], acc[tt][nt], 0, 0, 0); \
    __builtin_amdgcn_s_setprio(0);

    LOADB(b0, 0);
#pragma unroll
    for (int i = 0; i < 16; ++i) {       // stage ALL of A (64 KB): layout-agnostic 1 KiB chunks
        int c = wv * 16 + i;
        async16(abase + (c << 10) + (ln << 4), lds + (c << 10));
    }
    LOADB(b1, 1);
    __syncthreads();                     // drains global_load_lds; A resident for every wave

    { FRAGS(0); DOMFMA(b0); }
    __builtin_amdgcn_sched_barrier(0);
    { LOADB(b0, 2); FRAGS(1); DOMFMA(b1); }
    __builtin_amdgcn_sched_barrier(0);
    { LOADB(b1, 3); FRAGS(2); DOMFMA(b0); }
    __builtin_amdgcn_sched_barrier(0);
    { FRAGS(3); DOMFMA(b1); }

    __syncthreads();                     // ALL waves done reading A -> safe to reuse lds[0:4096)
    unsigned long long* s1 = (unsigned long long*)lds;          // [128][2]
    unsigned long long* s2 = (unsigned long long*)(lds + 2048); // [128][2]

    // top-2 per token over this block's 128 cols.
    // token = mh*64 + tt*32 + (ln&31); n = nh*64 + nt*32 + (reg&3) + 8*(reg>>2) + 4*(ln>>5)
    int colt = ln & 31, half = ln >> 5;
    unsigned hb = (unsigned)(1 - half) << 5;   // origin-half bit [5], inverted (smaller n-offset wins ties)
    int nbase0 = by * 128 + nh * 64;
#pragma unroll
    for (int tt = 0; tt < 2; ++tt) {
        // index-free top-2: 5-bit slot id in low mantissa; med3/max scan over 32 regs.
        float v1 = -3.0f, v2 = -3.5f;
#pragma unroll
        for (int nt = 0; nt < 2; ++nt)
#pragma unroll
            for (int rg = 0; rg < 16; ++rg) {
                unsigned e = 31u - (unsigned)(nt * 16 + rg);
                float pv = __uint_as_float((__float_as_uint(acc[tt][nt][rg]) & 0xFFFFFFE0u) | e);
                v2 = __builtin_amdgcn_fmed3f(v1, v2, pv);
                v1 = fmaxf(v1, pv);
            }
        // embed origin half in bit [5]; re-sort (masking can invert near-ties)
        float w1 = __uint_as_float((__float_as_uint(v1) & 0xFFFFFFDFu) | hb);
        float w2 = __uint_as_float((__float_as_uint(v2) & 0xFFFFFFDFu) | hb);
        v1 = fmaxf(w1, w2);
        v2 = fminf(w1, w2);
        // single cross-half merge (ln <-> ln+32)
        {
            float p1 = __shfl_xor(v1, 32);
            float p2 = __shfl_xor(v2, 32);
            v2 = __builtin_amdgcn_fmed3f(v1, p1, fmaxf(v2, p2));
            v1 = fmaxf(v1, p1);
        }
        if (half == 0) {
            unsigned u1 = __float_as_uint(v1), u2 = __float_as_uint(v2);
            int sA = 31 - (int)(u1 & 31u), hA = 1 - (int)((u1 >> 5) & 1u);
            int sB = 31 - (int)(u2 & 31u), hB = 1 - (int)((u2 >> 5) & 1u);
            int n1 = (sA >> 4) * 32 + ((sA & 15) & 3) + 8 * ((sA & 15) >> 2) + 4 * hA;
            int n2 = (sB >> 4) * 32 + ((sB & 15) & 3) + 8 * ((sB & 15) >> 2) + 4 * hB;
            int row = mh * 64 + tt * 32 + colt;
            s1[row * 2 + nh] = key64(v1, nbase0 + n1);
            s2[row * 2 + nh] = key64(v2, nbase0 + n2);
        }
    }
    __syncthreads();
    if (tid < 128) {
        unsigned long long k1 = s1[tid * 2], k2 = s2[tid * 2];
        merge2(k1, k2, s1[tid * 2 + 1], s2[tid * 2 + 1]);
        ulonglong2 v; v.x = k1; v.y = k2;
        ((ulonglong2*)pb)[((size_t)(bx * 128 + tid)) * 128 + by] = v;
    }
#undef LOADB
#undef FRAGS
#undef DOMFMA
}

// ---------- per token: G over block tops; exact fp32 verify only when >1 candidate passes T ----------
__global__ __launch_bounds__(256) void k_gather(const unsigned long long* __restrict__ pb,
                                                const float* __restrict__ W, const float* __restrict__ tok,
                                                const float* __restrict__ cls,
                                                const float* __restrict__ ntok, const float* __restrict__ nw,
                                                float* __restrict__ out, int* __restrict__ idxbuf,
                                                float* __restrict__ lossbuf, unsigned int* __restrict__ used) {
    __shared__ float lp[4];
    int tid = threadIdx.x;
    int t = blockIdx.x * 4 + (tid >> 6);
    int ln = tid & 63, w = tid >> 6;
    const ulonglong2* pv = (const ulonglong2*)pb;
    ulonglong2 ea = pv[(size_t)t * 128 + ln];
    ulonglong2 eb = pv[(size_t)t * 128 + 64 + ln];
    unsigned long long g = ea.x > eb.x ? ea.x : eb.x;
#pragma unroll
    for (int off = 1; off < 64; off <<= 1) {
        unsigned long long o = __shfl_xor(g, off);
        if (o > g) g = o;
    }
    float T = keyval(g) - MWIN;
    int tq = t / 257, ts = t - tq * 257;
    const float* xrow = (ts == 0) ? (cls + (size_t)tq * 256) : (tok + (size_t)t * 256);
    f4 xv = *(const f4*)&xrow[ln * 4];
    unsigned long long k4[4] = {ea.x, ea.y, eb.x, eb.y};
    unsigned long long msk[4];
    int total = 0;
#pragma unroll
    for (int gi = 0; gi < 4; ++gi) {
        msk[gi] = __ballot(keyval(k4[gi]) >= T);
        total += __popcll(msk[gi]);
    }
    int besti;
    if (total == 1) {
        // lone candidate above the rigorous window IS the argmax (true argmax always passes T)
        unsigned long long ck = 0;
#pragma unroll
        for (int gi = 0; gi < 4; ++gi)
            if (msk[gi]) { int src = __ffsll(msk[gi]) - 1; ck = __shfl(k4[gi], src); }
        besti = (int)(~(unsigned)(ck & 0xffffffffu));
    } else {
        float nt = ntok[t];
        float bestv = -3.0f;
        besti = 0x7fffffff;
#pragma unroll
        for (int gi = 0; gi < 4; ++gi) {
            unsigned long long mask = msk[gi];
            while (mask) {
                int src = __ffsll(mask) - 1;
                mask &= mask - 1;
                unsigned long long ck = __shfl(k4[gi], src);
                int ci = (int)(~(unsigned)(ck & 0xffffffffu));
                f4 wc = *(const f4*)&W[(size_t)ci * 256 + ln * 4];
                float d = xv.x * wc.x + xv.y * wc.y + xv.z * wc.z + xv.w * wc.w;
#pragma unroll
                for (int off = 1; off < 64; off <<= 1) d += __shfl_xor(d, off);
                float sim = d / (nt * nw[ci]);
                if (sim > bestv || (sim == bestv && ci < besti)) { bestv = sim; besti = ci; }
            }
        }
    }
    int bi = besti;
    f4 wr = *(const f4*)&W[(size_t)bi * 256 + ln * 4];
    float dx = wr.x - xv.x, dy = wr.y - xv.y, dz = wr.z - xv.z, dw = wr.w - xv.w;
    float ls = dx * dx + dy * dy + dz * dz + dw * dw;
#pragma unroll
    for (int off = 1; off < 64; off <<= 1) ls += __shfl_xor(ls, off);
    if (ln == 0) {
        lp[w] = ls;
        atomicOr(&used[bi >> 5], 1u << (bi & 31));
        idxbuf[t] = bi;
    }
    if (ts == 0) {
        *(f4*)&out[tq * 256 + ln * 4] = wr;          // fhat_class
    }
    __syncthreads();
    if (tid == 0) lossbuf[blockIdx.x] = lp[0] + lp[1] + lp[2] + lp[3];
}

// ---------- fhat_patch scatter via LDS transpose (coalesced writes) + fused final reduction ----------
__global__ __launch_bounds__(256) void k_scatter(const int* __restrict__ idxbuf, const float* __restrict__ W,
                                                 float* __restrict__ out, const unsigned int* __restrict__ used,
                                                 const float* __restrict__ lossbuf) {
    __shared__ float t64[64][65];
    __shared__ int sidx[64];
    int c0 = blockIdx.x * 64, p0 = blockIdx.y * 64, b = blockIdx.z;
    int tid = threadIdx.x;
    if (tid < 64) sidx[tid] = idxbuf[b * 257 + 1 + p0 + tid];
    __syncthreads();
    int l = tid & 63, w = tid >> 6;
#pragma unroll
    for (int i = 0; i < 16; ++i) {
        int p = i * 4 + w;
        t64[p][l] = W[(size_t)sidx[p] * 256 + c0 + l];
    }
    __syncthreads();
#pragma unroll
    for (int i = 0; i < 16; ++i) {
        int c = i * 4 + w;
        out[8192 + (size_t)b * 65536 + (size_t)(c0 + c) * 256 + p0 + l] = t64[l][c];
    }
    if (blockIdx.x == 0 && blockIdx.y == 0 && blockIdx.z == 0) {
        int cnt = 0;
        float ls = 0.0f;
        for (int i = tid; i < VOCAB / 32; i += 256) cnt += __popc(used[i]);
        for (int i = tid; i < NLOSS; i += 256) ls += lossbuf[i];
#pragma unroll
        for (int off = 32; off > 0; off >>= 1) {
            cnt += __shfl_down(cnt, off);
            ls += __shfl_down(ls, off);
        }
        __shared__ int p4f[4];
        __shared__ float f4s[4];
        if ((tid & 63) == 0) { p4f[tid >> 6] = cnt; f4s[tid >> 6] = ls; }
        __syncthreads();
        if (tid == 0) {
            int c = p4f[0] + p4f[1] + p4f[2] + p4f[3];
            float lsum = f4s[0] + f4s[1] + f4s[2] + f4s[3];
            out[8192 + 2097152] = 1.25f * lsum / (float)(NTOK * 256);      // vq_loss
            out[8192 + 2097152 + 1] = 100.0f * (float)c / (float)VOCAB;    // vocab_usage
        }
    }
}

extern "C" void kernel_launch(void* const* d_in, const int* in_sizes, int n_in,
                              void* d_out, int out_size, void* d_ws, size_t ws_size,
                              hipStream_t stream) {
    (void)in_sizes; (void)n_in; (void)out_size; (void)ws_size;
    const float* cls = (const float*)d_in[0];
    const float* patch = (const float*)d_in[1];
    const float* W = (const float*)d_in[2];
    float* out = (float*)d_out;

    char* ws = (char*)d_ws;
    float* tok = (float*)ws;                                   // 8224*256 f = 8.42 MB
    char* apk = ws + (size_t)NTOK * 256 * 4;                   // 65*65536  = 4.26 MB
    char* bpk = apk + (size_t)MTILES * TILE_BYTES;             // 128*65536 = 8.39 MB
    unsigned long long* pb = (unsigned long long*)(bpk + (size_t)NBY * TILE_BYTES);  // 8320*128*16 B = 17 MB
    float* ntokv = (float*)(pb + (size_t)MP * NBY * 2);        // 8320 f
    float* nwv = ntokv + MP;                                   // 16384 f
    float* lossbuf = nwv + VOCAB;                              // 2056 f
    int* idxbuf = (int*)(lossbuf + NLOSS);                     // 8224 i
    unsigned int* used = (unsigned int*)(idxbuf + NTOK);       // 512 u32

    k_prep<<<1536, 256, 0, stream>>>(patch, W, tok, bpk, nwv, used);
    k_packA<<<TOKCHUNKS, 256, 0, stream>>>(tok, cls, apk, ntokv);
    k_sim<<<MTILES * NBY, 256, 0, stream>>>(apk, bpk, pb);
    k_gather<<<NLOSS, 256, 0, stream>>>(pb, W, tok, cls, ntokv, nwv, out, idxbuf, lossbuf, used);
    k_scatter<<<dim3(4, 4, NB), 256, 0, stream>>>(idxbuf, W, out, used, lossbuf);
}

// Round 13
// 184.530 us; speedup vs baseline: 1.0623x; 1.0623x over previous
//
#include <hip/hip_runtime.h>
#include <stdint.h>

#define VOCAB 16384
#define NB 32
#define NTOK 8224      // 32*257
#define MTILES 65      // M tiles of 128 rows
#define MP 8320        // MTILES*128
#define NBY 128        // N tiles of 128 cols
#define TILE_BYTES 65536    // 128 rows x 256 K x 2B f16
#define NLOSS 2056          // loss partial blocks (NTOK/4)
#define MWIN 2.25e-3f       // |sim_f16 - sim_fp32| window (2*margin) + mantissa-embed slack
#define TOKCHUNKS 520       // token pack chunks

typedef _Float16 half8 __attribute__((ext_vector_type(8)));
typedef float f4 __attribute__((ext_vector_type(4)));
typedef __attribute__((address_space(1))) const uint32_t* gas_t;
typedef __attribute__((address_space(3))) uint32_t* las_t;

__device__ __forceinline__ void async16(const void* g, void* l) {
    __builtin_amdgcn_global_load_lds((gas_t)g, (las_t)l, 16, 0, 0);
}

__device__ __forceinline__ unsigned long long key64(float v, int idx) {
    unsigned u = __float_as_uint(v);
    u = (u & 0x80000000u) ? ~u : (u | 0x80000000u);
    return ((unsigned long long)u << 32) | (unsigned)(~idx);   // order: val desc, idx asc
}

__device__ __forceinline__ float keyval(unsigned long long k) {
    unsigned u = (unsigned)(k >> 32);
    u = (u & 0x80000000u) ? (u & 0x7fffffffu) : ~u;
    return __uint_as_float(u);
}

__device__ __forceinline__ void merge2(unsigned long long& k1, unsigned long long& k2,
                                       unsigned long long p1, unsigned long long p2) {
    unsigned long long lo = k1 < p1 ? k1 : p1;           // top-2 of {k1,k2,p1,p2}, k2<=k1, p2<=p1
    k1 = k1 > p1 ? k1 : p1;
    unsigned long long m2 = k2 > p2 ? k2 : p2;
    k2 = lo > m2 ? lo : m2;
}

// ---------- prep: patch transpose (blocks 0..511, id 0 zeroes used) || W pack (blocks 512..1535) ----------
// W-pack is independent of the patch transpose; running them in one grid removes the false
// serialization of W-pack behind k_patch. Shared LDS union keeps the kernel at ~18 KB LDS.
__global__ __launch_bounds__(256) void k_prep(const float* __restrict__ patch, const float* __restrict__ W,
                                              float* __restrict__ tok, char* __restrict__ bpk,
                                              float* __restrict__ nwv, unsigned int* __restrict__ used) {
    __shared__ float buf[4290];          // union: patch half uses [64][65]; W half uses [16][264]
    __shared__ float pr[16][16];
    __shared__ float sn[16];
    int id = blockIdx.x;
    int tid = threadIdx.x;
    if (id < 512) {
        if (id == 0) {
            for (int i = tid; i < VOCAB / 32; i += 256) used[i] = 0u;
        }
        int c0 = (id & 3) * 64, p0 = ((id >> 2) & 3) * 64, b = id >> 4;
        int l = tid & 63, w = tid >> 6;
        const float* src = patch + b * 65536;
#pragma unroll
        for (int i = 0; i < 16; ++i) {
            int row = i * 4 + w;
            buf[row * 65 + l] = src[(c0 + row) * 256 + p0 + l];
        }
        __syncthreads();
#pragma unroll
        for (int i = 0; i < 16; ++i) {
            int prow = i * 4 + w;
            tok[(b * 257 + 1 + p0 + prow) * 256 + c0 + l] = buf[l * 65 + prow];
        }
    } else {
        // W pack: g = id-512 in 0..1023, rows g*16 .. g*16+15 (exactly covers VOCAB)
        int g = id - 512;
        int row0 = g * 16;
        int rr = tid >> 4, cb = tid & 15;
        const float* sp = W + (size_t)(row0 + rr) * 256 + cb * 16;
        float psum = 0.0f;
#pragma unroll
        for (int i = 0; i < 4; ++i) {
            float4 v = *(const float4*)(sp + i * 4);
            *(float4*)&buf[rr * 264 + cb * 16 + i * 4] = v;
            psum += v.x * v.x + v.y * v.y + v.z * v.z + v.w * v.w;
        }
        pr[rr][cb] = psum;
        __syncthreads();
        if (tid < 16) {
            float s = 0.0f;
#pragma unroll
            for (int j = 0; j < 16; ++j) s += pr[tid][j];
            float nv = fmaxf(sqrtf(s), 1e-12f);
            sn[tid] = nv;
            nwv[row0 + tid] = nv;
        }
        __syncthreads();
        int c = tid & 63, pair = tid >> 6;
        int m = c & 15, jb = (c >> 4) * 8;
        float inv = 1.0f / sn[m];
        char* base = bpk + (size_t)(g >> 3) * TILE_BYTES + (size_t)(g & 7) * 1024 + c * 16;
#pragma unroll
        for (int it = 0; it < 2; ++it) {
            int k32 = it * 4 + pair;
            const float* rowp = &buf[m * 264 + k32 * 32 + jb];
            half8 o;
#pragma unroll
            for (int j = 0; j < 8; ++j) o[j] = (_Float16)(rowp[j] * inv);
            *(half8*)(base + (size_t)k32 * 8192) = o;
        }
    }
}

// ---------- token pack: normalized rows -> f16, MFMA fragment order; saves norms ----------
__global__ __launch_bounds__(256) void k_packA(const float* __restrict__ tok, const float* __restrict__ cls,
                                               char* __restrict__ apk, float* __restrict__ ntokv) {
    __shared__ float t[16][264];
    __shared__ float pr[16][16];
    __shared__ float sn[16];
    int g = blockIdx.x;              // 16-row chunk id, 0..519
    int row0 = g * 16;
    int tid = threadIdx.x;
    int rr = tid >> 4, cb = tid & 15;
    int grow = row0 + rr;
    int b = grow / 257, s = grow - b * 257;
    const float* sp = (s == 0 && grow < NTOK) ? (cls + (size_t)b * 256 + cb * 16)
                                              : (tok + (size_t)grow * 256 + cb * 16);
    float psum = 0.0f;
#pragma unroll
    for (int i = 0; i < 4; ++i) {
        float4 v = (grow < NTOK) ? *(const float4*)(sp + i * 4) : make_float4(0.f, 0.f, 0.f, 0.f);
        *(float4*)&t[rr][cb * 16 + i * 4] = v;
        psum += v.x * v.x + v.y * v.y + v.z * v.z + v.w * v.w;
    }
    pr[rr][cb] = psum;
    __syncthreads();
    if (tid < 16) {
        float s2 = 0.0f;
#pragma unroll
        for (int j = 0; j < 16; ++j) s2 += pr[tid][j];
        float nv = fmaxf(sqrtf(s2), 1e-12f);
        sn[tid] = nv;
        ntokv[row0 + tid] = nv;
    }
    __syncthreads();
    int c = tid & 63, pair = tid >> 6;
    int m = c & 15, jb = (c >> 4) * 8;
    float inv = 1.0f / sn[m];
    char* base = apk + (size_t)(g >> 3) * TILE_BYTES + (size_t)(g & 7) * 1024 + c * 16;
#pragma unroll
    for (int it = 0; it < 2; ++it) {
        int k32 = it * 4 + pair;
        const float* rowp = &t[m][k32 * 32 + jb];
        half8 o;
#pragma unroll
        for (int j = 0; j < 8; ++j) o[j] = (_Float16)(rowp[j] * inv);
        *(half8*)(base + (size_t)k32 * 8192) = o;
    }
}

// ---------- sim: f16 MFMA; A staged whole-tile in LDS (once), B direct global->reg ----------
// R5/R9/R11 structure verbatim (best measured: 98.5 us). OPERAND-SWAPPED mfma(B,A) -> C^T.
// 16x16x32 shape retained deliberately: acc[4][4] = 16 independent MFMA chains (ILP); the
// 32x32x16 variant (R12) has only 4 chains and regressed 14% despite higher per-op rate.
__global__ __launch_bounds__(256) void k_sim(const char* __restrict__ apk, const char* __restrict__ bpk,
                                             unsigned long long* __restrict__ pb) {
    __shared__ char lds[65536];                        // A: 4 phases x 16 KB, never overwritten
    // XCD-aware supertile swizzle (R4-proven: FETCH 602->90 MB)
    int id = blockIdx.x;             // 0..8319
    int xcd = id & 7, r = id >> 3;
    int st = r / 104, within = r % 104;
    int stid = xcd * 10 + st;        // 0..79
    int sx = stid % 5, sy = stid / 5;
    int bx = sx * 13 + within % 13;  // 0..64
    int by = sy * 8 + within / 13;   // 0..127

    int tid = threadIdx.x;
    int ln = tid & 63, wv = tid >> 6;
    int mh = wv >> 1, nh = wv & 1;
    const char* abase = apk + (size_t)bx * TILE_BYTES;
    const half8* Bg = (const half8*)(bpk + (size_t)by * TILE_BYTES);   // frag (p*16+s*8+nh*4+ni)*64+ln

    f4 acc[4][4];
#pragma unroll
    for (int i = 0; i < 4; ++i)
#pragma unroll
        for (int j = 0; j < 4; ++j) acc[i][j] = (f4){0.f, 0.f, 0.f, 0.f};

    half8 b0[2][4], b1[2][4];
#define LOADB(DST, P)                                                                 \
    _Pragma("unroll")                                                                 \
    for (int s = 0; s < 2; ++s)                                                       \
        _Pragma("unroll")                                                             \
        for (int ni = 0; ni < 4; ++ni)                                                \
            DST[s][ni] = Bg[((P) * 16 + s * 8 + nh * 4 + ni) * 64 + ln];

#define FRAGS(P)                                                                      \
    half8 ah[2][4];                                                                   \
    _Pragma("unroll")                                                                 \
    for (int s = 0; s < 2; ++s) {                                                     \
        const half8* Af = (const half8*)(lds + (P) * 16384 + s * 8192);               \
        _Pragma("unroll")                                                             \
        for (int mi = 0; mi < 4; ++mi) ah[s][mi] = Af[(mh * 4 + mi) * 64 + ln];       \
    }

#define DOMFMA(BH)                                                                    \
    __builtin_amdgcn_s_setprio(1);                                                    \
    _Pragma("unroll")                                                                 \
    for (int s = 0; s < 2; ++s)                                                       \
        _Pragma("unroll")                                                             \
        for (int mi = 0; mi < 4; ++mi)                                                \
            _Pragma("unroll")                                                         \
            for (int ni = 0; ni < 4; ++ni)                                            \
                acc[mi][ni] = __builtin_amdgcn_mfma_f32_16x16x32_f16(BH[s][ni], ah[s][mi], acc[mi][ni], 0, 0, 0); \
    __builtin_amdgcn_s_setprio(0);

    LOADB(b0, 0);
#pragma unroll
    for (int i = 0; i < 16; ++i) {       // stage ALL of A (64 KB): wave wv stages phase wv
        int c = wv * 16 + i;
        async16(abase + (c << 10) + (ln << 4), lds + (c << 10));
    }
    LOADB(b1, 1);
    __syncthreads();                     // drains global_load_lds; A resident for every wave

    { FRAGS(0); DOMFMA(b0); }
    __builtin_amdgcn_sched_barrier(0);
    { LOADB(b0, 2); FRAGS(1); DOMFMA(b1); }
    __builtin_amdgcn_sched_barrier(0);
    { LOADB(b1, 3); FRAGS(2); DOMFMA(b0); }
    __builtin_amdgcn_sched_barrier(0);
    { FRAGS(3); DOMFMA(b1); }

    __syncthreads();                     // ALL waves done reading A -> safe to reuse lds[0:4096)
    unsigned long long* s1 = (unsigned long long*)lds;          // [128][2]
    unsigned long long* s2 = (unsigned long long*)(lds + 2048); // [128][2]

    // top-2 per token row over this block's 128 cols.
    // C^T layout: token = mh*64 + mi*16 + (ln&15); n = nh*64 + ni*16 + quad*4 + rg
    int col = ln & 15, quad = ln >> 4;
    unsigned qb = (unsigned)(3 - quad) << 4;   // origin-quad bits [5:4], inverted (smaller quad wins ties)
    int nbase0 = by * 128 + nh * 64;
#pragma unroll
    for (int mi = 0; mi < 4; ++mi) {
        // index-free top-2: slot id (4b) in low mantissa; med3/max scan.
        float v1 = -3.0f, v2 = -3.5f;
#pragma unroll
        for (int ni = 0; ni < 4; ++ni)
#pragma unroll
            for (int rg = 0; rg < 4; ++rg) {
                unsigned e = 15u - (unsigned)(ni * 4 + rg);
                float pv = __uint_as_float((__float_as_uint(acc[mi][ni][rg]) & 0xFFFFFFF0u) | e);
                v2 = __builtin_amdgcn_fmed3f(v1, v2, pv);
                v1 = fmaxf(v1, pv);
            }
        // embed origin quad in bits [5:4]; re-sort (masking can invert near-ties)
        float w1 = __uint_as_float((__float_as_uint(v1) & 0xFFFFFFCFu) | qb);
        float w2 = __uint_as_float((__float_as_uint(v2) & 0xFFFFFFCFu) | qb);
        v1 = fmaxf(w1, w2);
        v2 = fminf(w1, w2);
        // cross-quad merge in float domain (32-bit shuffles, med3 top-2 merge)
#pragma unroll
        for (int off = 16; off < 64; off <<= 1) {
            float p1 = __shfl_xor(v1, off);
            float p2 = __shfl_xor(v2, off);
            v2 = __builtin_amdgcn_fmed3f(v1, p1, fmaxf(v2, p2));
            v1 = fmaxf(v1, p1);
        }
        if (quad == 0) {
            unsigned u1 = __float_as_uint(v1), u2 = __float_as_uint(v2);
            int q1 = 3 - (int)((u1 >> 4) & 3u), o1 = 15 - (int)(u1 & 15u);
            int q2 = 3 - (int)((u2 >> 4) & 3u), o2 = 15 - (int)(u2 & 15u);
            int n1 = ((o1 >> 2) << 4) + q1 * 4 + (o1 & 3);
            int n2 = ((o2 >> 2) << 4) + q2 * 4 + (o2 & 3);
            int row = mh * 64 + mi * 16 + col;
            s1[row * 2 + nh] = key64(v1, nbase0 + n1);
            s2[row * 2 + nh] = key64(v2, nbase0 + n2);
        }
    }
    __syncthreads();
    if (tid < 128) {
        unsigned long long k1 = s1[tid * 2], k2 = s2[tid * 2];
        merge2(k1, k2, s1[tid * 2 + 1], s2[tid * 2 + 1]);
        ulonglong2 v; v.x = k1; v.y = k2;
        ((ulonglong2*)pb)[((size_t)(bx * 128 + tid)) * 128 + by] = v;
    }
#undef LOADB
#undef FRAGS
#undef DOMFMA
}

// ---------- per token: G over block tops; exact fp32 verify only when >1 candidate passes T ----------
__global__ __launch_bounds__(256) void k_gather(const unsigned long long* __restrict__ pb,
                                                const float* __restrict__ W, const float* __restrict__ tok,
                                                const float* __restrict__ cls,
                                                const float* __restrict__ ntok, const float* __restrict__ nw,
                                                float* __restrict__ out, int* __restrict__ idxbuf,
                                                float* __restrict__ lossbuf, unsigned int* __restrict__ used) {
    __shared__ float lp[4];
    int tid = threadIdx.x;
    int t = blockIdx.x * 4 + (tid >> 6);
    int ln = tid & 63, w = tid >> 6;
    const ulonglong2* pv = (const ulonglong2*)pb;
    ulonglong2 ea = pv[(size_t)t * 128 + ln];
    ulonglong2 eb = pv[(size_t)t * 128 + 64 + ln];
    unsigned long long g = ea.x > eb.x ? ea.x : eb.x;
#pragma unroll
    for (int off = 1; off < 64; off <<= 1) {
        unsigned long long o = __shfl_xor(g, off);
        if (o > g) g = o;
    }
    float T = keyval(g) - MWIN;
    int tq = t / 257, ts = t - tq * 257;
    const float* xrow = (ts == 0) ? (cls + (size_t)tq * 256) : (tok + (size_t)t * 256);
    f4 xv = *(const f4*)&xrow[ln * 4];
    unsigned long long k4[4] = {ea.x, ea.y, eb.x, eb.y};
    unsigned long long msk[4];
    int total = 0;
#pragma unroll
    for (int gi = 0; gi < 4; ++gi) {
        msk[gi] = __ballot(keyval(k4[gi]) >= T);
        total += __popcll(msk[gi]);
    }
    int besti;
    if (total == 1) {
        // lone candidate above the rigorous window IS the argmax (true argmax always passes T)
        unsigned long long ck = 0;
#pragma unroll
        for (int gi = 0; gi < 4; ++gi)
            if (msk[gi]) { int src = __ffsll(msk[gi]) - 1; ck = __shfl(k4[gi], src); }
        besti = (int)(~(unsigned)(ck & 0xffffffffu));
    } else {
        float nt = ntok[t];
        float bestv = -3.0f;
        besti = 0x7fffffff;
#pragma unroll
        for (int gi = 0; gi < 4; ++gi) {
            unsigned long long mask = msk[gi];
            while (mask) {
                int src = __ffsll(mask) - 1;
                mask &= mask - 1;
                unsigned long long ck = __shfl(k4[gi], src);
                int ci = (int)(~(unsigned)(ck & 0xffffffffu));
                f4 wc = *(const f4*)&W[(size_t)ci * 256 + ln * 4];
                float d = xv.x * wc.x + xv.y * wc.y + xv.z * wc.z + xv.w * wc.w;
#pragma unroll
                for (int off = 1; off < 64; off <<= 1) d += __shfl_xor(d, off);
                float sim = d / (nt * nw[ci]);
                if (sim > bestv || (sim == bestv && ci < besti)) { bestv = sim; besti = ci; }
            }
        }
    }
    int bi = besti;
    f4 wr = *(const f4*)&W[(size_t)bi * 256 + ln * 4];
    float dx = wr.x - xv.x, dy = wr.y - xv.y, dz = wr.z - xv.z, dw = wr.w - xv.w;
    float ls = dx * dx + dy * dy + dz * dz + dw * dw;
#pragma unroll
    for (int off = 1; off < 64; off <<= 1) ls += __shfl_xor(ls, off);
    if (ln == 0) {
        lp[w] = ls;
        atomicOr(&used[bi >> 5], 1u << (bi & 31));
        idxbuf[t] = bi;
    }
    if (ts == 0) {
        *(f4*)&out[tq * 256 + ln * 4] = wr;          // fhat_class
    }
    __syncthreads();
    if (tid == 0) lossbuf[blockIdx.x] = lp[0] + lp[1] + lp[2] + lp[3];
}

// ---------- fhat_patch scatter via LDS transpose (coalesced writes) + fused final reduction ----------
__global__ __launch_bounds__(256) void k_scatter(const int* __restrict__ idxbuf, const float* __restrict__ W,
                                                 float* __restrict__ out, const unsigned int* __restrict__ used,
                                                 const float* __restrict__ lossbuf) {
    __shared__ float t64[64][65];
    __shared__ int sidx[64];
    int c0 = blockIdx.x * 64, p0 = blockIdx.y * 64, b = blockIdx.z;
    int tid = threadIdx.x;
    if (tid < 64) sidx[tid] = idxbuf[b * 257 + 1 + p0 + tid];
    __syncthreads();
    int l = tid & 63, w = tid >> 6;
#pragma unroll
    for (int i = 0; i < 16; ++i) {
        int p = i * 4 + w;
        t64[p][l] = W[(size_t)sidx[p] * 256 + c0 + l];
    }
    __syncthreads();
#pragma unroll
    for (int i = 0; i < 16; ++i) {
        int c = i * 4 + w;
        out[8192 + (size_t)b * 65536 + (size_t)(c0 + c) * 256 + p0 + l] = t64[l][c];
    }
    if (blockIdx.x == 0 && blockIdx.y == 0 && blockIdx.z == 0) {
        int cnt = 0;
        float ls = 0.0f;
        for (int i = tid; i < VOCAB / 32; i += 256) cnt += __popc(used[i]);
        for (int i = tid; i < NLOSS; i += 256) ls += lossbuf[i];
#pragma unroll
        for (int off = 32; off > 0; off >>= 1) {
            cnt += __shfl_down(cnt, off);
            ls += __shfl_down(ls, off);
        }
        __shared__ int p4f[4];
        __shared__ float f4s[4];
        if ((tid & 63) == 0) { p4f[tid >> 6] = cnt; f4s[tid >> 6] = ls; }
        __syncthreads();
        if (tid == 0) {
            int c = p4f[0] + p4f[1] + p4f[2] + p4f[3];
            float lsum = f4s[0] + f4s[1] + f4s[2] + f4s[3];
            out[8192 + 2097152] = 1.25f * lsum / (float)(NTOK * 256);      // vq_loss
            out[8192 + 2097152 + 1] = 100.0f * (float)c / (float)VOCAB;    // vocab_usage
        }
    }
}

extern "C" void kernel_launch(void* const* d_in, const int* in_sizes, int n_in,
                              void* d_out, int out_size, void* d_ws, size_t ws_size,
                              hipStream_t stream) {
    (void)in_sizes; (void)n_in; (void)out_size; (void)ws_size;
    const float* cls = (const float*)d_in[0];
    const float* patch = (const float*)d_in[1];
    const float* W = (const float*)d_in[2];
    float* out = (float*)d_out;

    char* ws = (char*)d_ws;
    float* tok = (float*)ws;                                   // 8224*256 f = 8.42 MB
    char* apk = ws + (size_t)NTOK * 256 * 4;                   // 65*65536  = 4.26 MB
    char* bpk = apk + (size_t)MTILES * TILE_BYTES;             // 128*65536 = 8.39 MB
    unsigned long long* pb = (unsigned long long*)(bpk + (size_t)NBY * TILE_BYTES);  // 8320*128*16 B = 17 MB
    float* ntokv = (float*)(pb + (size_t)MP * NBY * 2);        // 8320 f
    float* nwv = ntokv + MP;                                   // 16384 f
    float* lossbuf = nwv + VOCAB;                              // 2056 f
    int* idxbuf = (int*)(lossbuf + NLOSS);                     // 8224 i
    unsigned int* used = (unsigned int*)(idxbuf + NTOK);       // 512 u32

    k_prep<<<1536, 256, 0, stream>>>(patch, W, tok, bpk, nwv, used);
    k_packA<<<TOKCHUNKS, 256, 0, stream>>>(tok, cls, apk, ntokv);
    k_sim<<<MTILES * NBY, 256, 0, stream>>>(apk, bpk, pb);
    k_gather<<<NLOSS, 256, 0, stream>>>(pb, W, tok, cls, ntokv, nwv, out, idxbuf, lossbuf, used);
    k_scatter<<<dim3(4, 4, NB), 256, 0, stream>>>(idxbuf, W, out, used, lossbuf);
}